// Round 1
// baseline (96406.750 us; speedup 1.0000x reference)
//
#include <hip/hip_runtime.h>
#include <cmath>

#define NN 68

// Wilson-Cowan neural mass model, 200k sequential Euler steps.
// Single block, 68 threads (thread j owns node j). C row in registers,
// E broadcast through double-buffered LDS. conn lags one step in the
// reference (conn_t = C @ E_{t-1}), so conn_{t+1} is computed during
// step t's elementwise update -- natural pipelining, one barrier/step.
__global__ __launch_bounds__(NN, 1)
void nmm_kernel(const float* __restrict__ params,
                const float* __restrict__ Cjk,
                const float* __restrict__ y0,
                float* __restrict__ out,
                const int num_steps)
{
#pragma clang fp contract(off)   // match numpy's separate mul/add rounding
    const int j = threadIdx.x;   // 0..67
    __shared__ __align__(16) float E_lds[2][NN];

    const float tau_e = params[0];
    const float tau_i = params[1];
    const float c1 = params[2];
    const float c2 = params[3];
    const float c3 = params[4];
    const float c4 = params[5];
    const float c5 = params[6];
    const float Pp = params[7];
    const float kE = params[8];
    const float kI = params[9];

    // sigmoid(0) offsets: 1/(1+exp(a*thr)), constants
    const float s0E = 1.0f / (1.0f + expf(1.3f * 4.0f));
    const float s0I = 1.0f / (1.0f + expf(2.0f * 3.7f));

    // C row j into registers (one-time load)
    float Crow[NN];
#pragma unroll
    for (int k = 0; k < NN; ++k) Crow[k] = Cjk[j * NN + k];

    float E = y0[j];
    float I = y0[NN + j];

    E_lds[0][j] = E;
    // raw barrier: LDS-wait only, do NOT drain global stores (vmcnt)
    asm volatile("s_waitcnt lgkmcnt(0)\ns_barrier" ::: "memory");

    // conn_0 = C @ E_0  (reference step 0 uses E_prev = y0[:N])
    float conn;
    {
        float a0 = 0.f, a1 = 0.f, a2 = 0.f, a3 = 0.f;
#pragma unroll
        for (int k4 = 0; k4 < NN / 4; ++k4) {
            const float4 e = *reinterpret_cast<const float4*>(&E_lds[0][4 * k4]);
            a0 = fmaf(Crow[4 * k4 + 0], e.x, a0);
            a1 = fmaf(Crow[4 * k4 + 1], e.y, a1);
            a2 = fmaf(Crow[4 * k4 + 2], e.z, a2);
            a3 = fmaf(Crow[4 * k4 + 3], e.w, a3);
        }
        conn = (a0 + a1) + (a2 + a3);
    }

    float* op = out + (size_t)j * (size_t)num_steps;

    for (int t = 0; t < num_steps; ++t) {
        const int cur = t & 1;

        // conn_{t+1} = C @ E_t  (independent FMA chain; compiler interleaves
        // it with the exp/div latency of the elementwise update below)
        float a0 = 0.f, a1 = 0.f, a2 = 0.f, a3 = 0.f;
#pragma unroll
        for (int k4 = 0; k4 < NN / 4; ++k4) {
            const float4 e = *reinterpret_cast<const float4*>(&E_lds[cur][4 * k4]);
            a0 = fmaf(Crow[4 * k4 + 0], e.x, a0);
            a1 = fmaf(Crow[4 * k4 + 1], e.y, a1);
            a2 = fmaf(Crow[4 * k4 + 2], e.z, a2);
            a3 = fmaf(Crow[4 * k4 + 3], e.w, a3);
        }

        // elementwise update using conn_t (computed during previous step)
        const float xE = c1 * E - c2 * I + c5 * conn + Pp;
        const float Se = 1.0f / (1.0f + expf(-1.3f * (xE - 4.0f))) - s0E;
        const float dE = (-E + (kE - E) * Se) / tau_e;   // rE = 1
        const float xI = c3 * E - c4 * I;                // Q = 0
        const float Si = 1.0f / (1.0f + expf(-2.0f * (xI - 3.7f))) - s0I;
        const float dI = (-I + (kI - I) * Si) / tau_i;   // rI = 1
        E = E + dE;   // DT = 1.0
        I = I + dI;
        op[t] = E - I;            // fire-and-forget store, never drained

        E_lds[cur ^ 1][j] = E;    // E_{t+1} for step t+1's matvec
        conn = (a0 + a1) + (a2 + a3);
        asm volatile("s_waitcnt lgkmcnt(0)\ns_barrier" ::: "memory");
    }
}

extern "C" void kernel_launch(void* const* d_in, const int* in_sizes, int n_in,
                              void* d_out, int out_size, void* d_ws, size_t ws_size,
                              hipStream_t stream) {
    const float* params = (const float*)d_in[0];
    const float* Cjk    = (const float*)d_in[1];
    const float* y0     = (const float*)d_in[2];
    // d_in[3] = Djk (unused by the reference dynamics)
    // d_in[4] = num_steps on device; host-side value derived from out_size
    const int num_steps = out_size / NN;

    nmm_kernel<<<dim3(1), dim3(NN), 0, stream>>>(
        params, Cjk, y0, (float*)d_out, num_steps);
}

// Round 2
// 85919.305 us; speedup vs baseline: 1.1221x; 1.1221x over previous
//
#include <hip/hip_runtime.h>
#include <cmath>

#define NN   68     // nodes
#define NPAD 72     // E buffer padded to 2 chunks of 36 (144 B, 16B-aligned)
#define HALF 36     // K-chunk per thread
#define NT   136    // 2 threads per node (K-split), 3 waves

// lane XOR 1 within quad via DPP quad_perm [1,0,3,2] -- pure VALU, no LDS
__device__ __forceinline__ float dpp_xor1(float x) {
    return __int_as_float(
        __builtin_amdgcn_mov_dpp(__float_as_int(x), 0xB1, 0xF, 0xF, true));
}

#define MAC(q, e)                 \
    a0 = fmaf(q.x, e.x, a0);      \
    a1 = fmaf(q.y, e.y, a1);      \
    a2 = fmaf(q.z, e.z, a2);      \
    a3 = fmaf(q.w, e.w, a3);

__global__ __launch_bounds__(NT, 1)
void nmm_kernel(const float* __restrict__ params,
                const float* __restrict__ Cjk,
                const float* __restrict__ y0,
                float* __restrict__ out,
                const int num_steps)
{
#pragma clang fp contract(off)   // match numpy's separate mul/add rounding
    const int tid = threadIdx.x;
    const int j   = tid >> 1;    // node 0..67
    const int s   = tid & 1;     // K-half 0/1

    __shared__ __align__(16) float E_lds[2][NPAD];

    const float tau_e = params[0], tau_i = params[1];
    const float P1 = params[2], P2 = params[3], P3 = params[4];
    const float P4 = params[5], P5 = params[6], Pp = params[7];
    const float kE = params[8], kI = params[9];
    const float s0E = 1.0f / (1.0f + expf(1.3f * 4.0f));
    const float s0I = 1.0f / (1.0f + expf(2.0f * 3.7f));

    // C-row half chunk in 9 NAMED float4s -> guaranteed VGPR residency.
    // s=1's last quad covers k=68..71 (pad) -> zeros, also avoids OOB load.
    const float* crow = Cjk + j * NN + s * HALF;
    const float4 q0 = *(const float4*)(crow +  0);
    const float4 q1 = *(const float4*)(crow +  4);
    const float4 q2 = *(const float4*)(crow +  8);
    const float4 q3 = *(const float4*)(crow + 12);
    const float4 q4 = *(const float4*)(crow + 16);
    const float4 q5 = *(const float4*)(crow + 20);
    const float4 q6 = *(const float4*)(crow + 24);
    const float4 q7 = *(const float4*)(crow + 28);
    const float4 q8 = (s == 0) ? *(const float4*)(crow + 32)
                               : make_float4(0.f, 0.f, 0.f, 0.f);

    if (tid < NPAD) {
        E_lds[0][tid] = (tid < NN) ? y0[tid] : 0.0f;   // E_0 + zero pad
        E_lds[1][tid] = 0.0f;                          // pad zeros persist
    }
    float E = y0[j];
    float I = y0[NN + j];
    asm volatile("s_waitcnt lgkmcnt(0)\ns_barrier" ::: "memory");

    // conn_0 = C @ E_0 (reference step 0 uses E_prev = y0[:N])
    float conn;
    {
        const float* eb = &E_lds[0][s * HALF];
        const float4 e0 = ((const float4*)eb)[0], e1 = ((const float4*)eb)[1],
                     e2 = ((const float4*)eb)[2], e3 = ((const float4*)eb)[3],
                     e4 = ((const float4*)eb)[4], e5 = ((const float4*)eb)[5],
                     e6 = ((const float4*)eb)[6], e7 = ((const float4*)eb)[7],
                     e8 = ((const float4*)eb)[8];
        float a0 = 0.f, a1 = 0.f, a2 = 0.f, a3 = 0.f;
        MAC(q0, e0) MAC(q1, e1) MAC(q2, e2) MAC(q3, e3) MAC(q4, e4)
        MAC(q5, e5) MAC(q6, e6) MAC(q7, e7) MAC(q8, e8)
        const float p = (a0 + a1) + (a2 + a3);
        conn = p + dpp_xor1(p);   // both K-halves now hold full dot product
    }

    float* op = out + (size_t)j * (size_t)num_steps;

    for (int t = 0; t < num_steps; ++t) {
        const int cur = t & 1;

        // 1) issue E_t reads first; their ~120cy LDS latency hides under the
        //    register-only elementwise chain below
        const float* eb = &E_lds[cur][s * HALF];
        const float4 e0 = ((const float4*)eb)[0], e1 = ((const float4*)eb)[1],
                     e2 = ((const float4*)eb)[2], e3 = ((const float4*)eb)[3],
                     e4 = ((const float4*)eb)[4], e5 = ((const float4*)eb)[5],
                     e6 = ((const float4*)eb)[6], e7 = ((const float4*)eb)[7],
                     e8 = ((const float4*)eb)[8];

        // 2) elementwise update with conn_t (from previous iteration),
        //    bit-identical expressions to the absmax-0.0 round-1 kernel
        const float xE = P1 * E - P2 * I + P5 * conn + Pp;
        const float Se = 1.0f / (1.0f + expf(-1.3f * (xE - 4.0f))) - s0E;
        const float dE = (-E + (kE - E) * Se) / tau_e;    // rE = 1
        const float xI = P3 * E - P4 * I;                 // Q = 0
        const float Si = 1.0f / (1.0f + expf(-2.0f * (xI - 3.7f))) - s0I;
        const float dI = (-I + (kI - I) * Si) / tau_i;    // rI = 1
        const float En = E + dE;                          // DT = 1
        const float In = I + dI;

        // 3) publish: output store is fire-and-forget (never drained);
        //    E_{t+1} goes to the other LDS buffer
        if (s == 0) {
            op[t] = En - In;
            E_lds[cur ^ 1][j] = En;
        }

        // 4) conn_{t+1} = C @ E_t : 36 FMAs per thread, 4 accumulators
        float a0 = 0.f, a1 = 0.f, a2 = 0.f, a3 = 0.f;
        MAC(q0, e0) MAC(q1, e1) MAC(q2, e2) MAC(q3, e3) MAC(q4, e4)
        MAC(q5, e5) MAC(q6, e6) MAC(q7, e7) MAC(q8, e8)
        const float p = (a0 + a1) + (a2 + a3);
        conn = p + dpp_xor1(p);   // VALU cross-lane, identical in both lanes

        E = En; I = In;
        // LDS-only barrier: wait lgkm (reads + E write) but NOT vmcnt, so
        // the 200k output stores stay in flight
        asm volatile("s_waitcnt lgkmcnt(0)\ns_barrier" ::: "memory");
    }
}

extern "C" void kernel_launch(void* const* d_in, const int* in_sizes, int n_in,
                              void* d_out, int out_size, void* d_ws, size_t ws_size,
                              hipStream_t stream) {
    const float* params = (const float*)d_in[0];
    const float* Cjk    = (const float*)d_in[1];
    const float* y0     = (const float*)d_in[2];
    // d_in[3] = Djk (unused by the dynamics), d_in[4] = num_steps (device)
    const int num_steps = out_size / NN;

    nmm_kernel<<<dim3(1), dim3(NT), 0, stream>>>(
        params, Cjk, y0, (float*)d_out, num_steps);
}

// Round 3
// 83207.483 us; speedup vs baseline: 1.1586x; 1.0326x over previous
//
#include <hip/hip_runtime.h>
#include <cmath>

#define NN   68     // nodes
#define NPAD 72     // E buffer padded to 2 chunks of 36 (144 B, 16B-aligned)
#define HALF 36     // K-chunk per thread
#define NT   136    // 2 threads per node (K-split), 3 waves

// lane XOR 1 within quad via DPP quad_perm [1,0,3,2] -- pure VALU, no LDS
__device__ __forceinline__ float dpp_xor1(float x) {
    return __int_as_float(
        __builtin_amdgcn_mov_dpp(__float_as_int(x), 0xB1, 0xF, 0xF, true));
}

#define MAC(q, e)                 \
    a0 = fmaf(q.x, e.x, a0);      \
    a1 = fmaf(q.y, e.y, a1);      \
    a2 = fmaf(q.z, e.z, a2);      \
    a3 = fmaf(q.w, e.w, a3);

// Opaque register pin: after this, q is a register value with no memory
// provenance -- the barrier's "memory" clobber can no longer force a reload.
#define PIN4(q) asm volatile("" : "+v"(q.x), "+v"(q.y), "+v"(q.z), "+v"(q.w))

__global__ __launch_bounds__(NT, 1)
void nmm_kernel(const float* __restrict__ params,
                const float* __restrict__ Cjk,
                const float* __restrict__ y0,
                float* __restrict__ out,
                const int num_steps)
{
#pragma clang fp contract(off)   // match numpy's separate mul/add rounding
    const int tid = threadIdx.x;
    const int j   = tid >> 1;    // node 0..67
    const int s   = tid & 1;     // K-half 0/1

    __shared__ __align__(16) float E_lds[2][NPAD];

    const float tau_e = params[0], tau_i = params[1];
    const float P1 = params[2], P2 = params[3], P3 = params[4];
    const float P4 = params[5], P5 = params[6], Pp = params[7];
    const float kE = params[8], kI = params[9];
    const float s0E = 1.0f / (1.0f + expf(1.3f * 4.0f));
    const float s0I = 1.0f / (1.0f + expf(2.0f * 3.7f));

    // C-row half chunk -> 9 float4s, then PINNED into opaque VGPRs so they
    // stay loop-resident (round-2 lesson: without the pin, the asm barrier's
    // memory clobber forced 9 global reloads per step; VGPR_Count stuck at 48)
    const float* crow = Cjk + j * NN + s * HALF;
    float4 q0 = *(const float4*)(crow +  0);
    float4 q1 = *(const float4*)(crow +  4);
    float4 q2 = *(const float4*)(crow +  8);
    float4 q3 = *(const float4*)(crow + 12);
    float4 q4 = *(const float4*)(crow + 16);
    float4 q5 = *(const float4*)(crow + 20);
    float4 q6 = *(const float4*)(crow + 24);
    float4 q7 = *(const float4*)(crow + 28);
    float4 q8 = (s == 0) ? *(const float4*)(crow + 32)
                         : make_float4(0.f, 0.f, 0.f, 0.f);
    PIN4(q0); PIN4(q1); PIN4(q2); PIN4(q3); PIN4(q4);
    PIN4(q5); PIN4(q6); PIN4(q7); PIN4(q8);

    if (tid < NPAD) {
        E_lds[0][tid] = (tid < NN) ? y0[tid] : 0.0f;   // E_0 + zero pad
        E_lds[1][tid] = 0.0f;                          // pad zeros persist
    }
    float E = y0[j];
    float I = y0[NN + j];
    asm volatile("s_waitcnt lgkmcnt(0)\ns_barrier" ::: "memory");

    // conn_0 = C @ E_0 (reference step 0 uses E_prev = y0[:N])
    float conn;
    {
        const float* eb = &E_lds[0][s * HALF];
        const float4 e0 = ((const float4*)eb)[0], e1 = ((const float4*)eb)[1],
                     e2 = ((const float4*)eb)[2], e3 = ((const float4*)eb)[3],
                     e4 = ((const float4*)eb)[4], e5 = ((const float4*)eb)[5],
                     e6 = ((const float4*)eb)[6], e7 = ((const float4*)eb)[7],
                     e8 = ((const float4*)eb)[8];
        float a0 = 0.f, a1 = 0.f, a2 = 0.f, a3 = 0.f;
        MAC(q0, e0) MAC(q1, e1) MAC(q2, e2) MAC(q3, e3) MAC(q4, e4)
        MAC(q5, e5) MAC(q6, e6) MAC(q7, e7) MAC(q8, e8)
        const float p = (a0 + a1) + (a2 + a3);
        conn = p + dpp_xor1(p);   // both K-halves now hold full dot product
    }

    float* op = out + (size_t)j * (size_t)num_steps;

    for (int t = 0; t < num_steps; ++t) {
        const int cur = t & 1;

        // 1) issue E_t reads first; their LDS latency hides under the
        //    register-only elementwise chain below
        const float* eb = &E_lds[cur][s * HALF];
        const float4 e0 = ((const float4*)eb)[0], e1 = ((const float4*)eb)[1],
                     e2 = ((const float4*)eb)[2], e3 = ((const float4*)eb)[3],
                     e4 = ((const float4*)eb)[4], e5 = ((const float4*)eb)[5],
                     e6 = ((const float4*)eb)[6], e7 = ((const float4*)eb)[7],
                     e8 = ((const float4*)eb)[8];

        // 2) elementwise update with conn_t (from previous iteration),
        //    bit-identical expressions to the absmax-0.0 round-1 kernel
        const float xE = P1 * E - P2 * I + P5 * conn + Pp;
        const float Se = 1.0f / (1.0f + expf(-1.3f * (xE - 4.0f))) - s0E;
        const float dE = (-E + (kE - E) * Se) / tau_e;    // rE = 1
        const float xI = P3 * E - P4 * I;                 // Q = 0
        const float Si = 1.0f / (1.0f + expf(-2.0f * (xI - 3.7f))) - s0I;
        const float dI = (-I + (kI - I) * Si) / tau_i;    // rI = 1
        const float En = E + dE;                          // DT = 1
        const float In = I + dI;

        // 3) publish. Both K-split lanes hold identical En -> unconditional
        //    same-address same-value LDS write (2-way is free, m136).
        //    Global store stays predicated; fire-and-forget, never drained.
        E_lds[cur ^ 1][j] = En;
        if (s == 0) op[t] = En - In;

        // 4) conn_{t+1} = C @ E_t : 36 FMAs per thread, 4 accumulators
        float a0 = 0.f, a1 = 0.f, a2 = 0.f, a3 = 0.f;
        MAC(q0, e0) MAC(q1, e1) MAC(q2, e2) MAC(q3, e3) MAC(q4, e4)
        MAC(q5, e5) MAC(q6, e6) MAC(q7, e7) MAC(q8, e8)
        const float p = (a0 + a1) + (a2 + a3);
        conn = p + dpp_xor1(p);   // VALU cross-lane, identical in both lanes

        E = En; I = In;
        // LDS-only barrier: wait lgkm (reads + E write) but NOT vmcnt, so
        // the 200k output stores stay in flight
        asm volatile("s_waitcnt lgkmcnt(0)\ns_barrier" ::: "memory");
    }
}

extern "C" void kernel_launch(void* const* d_in, const int* in_sizes, int n_in,
                              void* d_out, int out_size, void* d_ws, size_t ws_size,
                              hipStream_t stream) {
    const float* params = (const float*)d_in[0];
    const float* Cjk    = (const float*)d_in[1];
    const float* y0     = (const float*)d_in[2];
    // d_in[3] = Djk (unused by the dynamics), d_in[4] = num_steps (device)
    const int num_steps = out_size / NN;

    nmm_kernel<<<dim3(1), dim3(NT), 0, stream>>>(
        params, Cjk, y0, (float*)d_out, num_steps);
}

// Round 4
// 47989.536 us; speedup vs baseline: 2.0089x; 1.7339x over previous
//
#include <hip/hip_runtime.h>
#include <cmath>

#define NN   68     // nodes
#define NPAD 72     // E buffer padded to 2 chunks of 36 (144 B, 16B-aligned)
#define HALF 36     // K-chunk per thread
#define NT   136    // 2 threads per node (K-split), 3 waves

// lane XOR 1 within quad via DPP quad_perm [1,0,3,2] -- pure VALU, no LDS
__device__ __forceinline__ float dpp_xor1(float x) {
    return __int_as_float(
        __builtin_amdgcn_mov_dpp(__float_as_int(x), 0xB1, 0xF, 0xF, true));
}

// fast hw ops: v_exp_f32 (2^x) and v_rcp_f32 (1/x), both ~1ulp-class
#if __has_builtin(__builtin_amdgcn_exp2f)
#define FAST_EXP2(x) __builtin_amdgcn_exp2f(x)
#else
#define FAST_EXP2(x) exp2f(x)
#endif
#define FAST_RCP(x) __builtin_amdgcn_rcpf(x)

#define MAC(q, e)                 \
    a0 = fmaf(q.x, e.x, a0);      \
    a1 = fmaf(q.y, e.y, a1);      \
    a2 = fmaf(q.z, e.z, a2);      \
    a3 = fmaf(q.w, e.w, a3);

// Opaque register pin (keeps C loads from being remat'd into the loop)
#define PIN4(q) asm volatile("" : "+v"(q.x), "+v"(q.y), "+v"(q.z), "+v"(q.w))

__global__ __launch_bounds__(NT, 1)
void nmm_kernel(const float* __restrict__ params,
                const float* __restrict__ Cjk,
                const float* __restrict__ y0,
                float* __restrict__ out,
                const int num_steps)
{
#pragma clang fp contract(off)
    const int tid = threadIdx.x;
    const int j   = tid >> 1;    // node 0..67
    const int s   = tid & 1;     // K-half 0/1

    __shared__ __align__(16) float E_lds[2][NPAD];

    const float tau_e = params[0], tau_i = params[1];
    const float P1 = params[2], P2 = params[3], P3 = params[4];
    const float P4 = params[5], P5 = params[6], Pp = params[7];
    const float kE = params[8], kI = params[9];

    // fast-sigmoid constants: exp(-a(x-thr)) = 2^(kX2*x + bX2)
    const float LOG2E = 1.4426950408889634f;
    const float kE2 = -1.3f * LOG2E, bE2 = (1.3f * 4.0f) * LOG2E;
    const float kI2 = -2.0f * LOG2E, bI2 = (2.0f * 3.7f) * LOG2E;
    const float s0E = 1.0f / (1.0f + expf(1.3f * 4.0f));   // once, precise
    const float s0I = 1.0f / (1.0f + expf(2.0f * 3.7f));
    const float inv_te = 1.0f / tau_e;                     // once, precise
    const float inv_ti = 1.0f / tau_i;

    // C-row half chunk -> 9 float4s, pinned
    const float* crow = Cjk + j * NN + s * HALF;
    float4 q0 = *(const float4*)(crow +  0);
    float4 q1 = *(const float4*)(crow +  4);
    float4 q2 = *(const float4*)(crow +  8);
    float4 q3 = *(const float4*)(crow + 12);
    float4 q4 = *(const float4*)(crow + 16);
    float4 q5 = *(const float4*)(crow + 20);
    float4 q6 = *(const float4*)(crow + 24);
    float4 q7 = *(const float4*)(crow + 28);
    float4 q8 = (s == 0) ? *(const float4*)(crow + 32)
                         : make_float4(0.f, 0.f, 0.f, 0.f);
    PIN4(q0); PIN4(q1); PIN4(q2); PIN4(q3); PIN4(q4);
    PIN4(q5); PIN4(q6); PIN4(q7); PIN4(q8);

    if (tid < NPAD) {
        E_lds[0][tid] = (tid < NN) ? y0[tid] : 0.0f;
        E_lds[1][tid] = 0.0f;
    }
    float E = y0[j];
    float I = y0[NN + j];
    asm volatile("s_waitcnt lgkmcnt(0)\ns_barrier" ::: "memory");

    // conn_0 = C @ E_0
    float conn;
    {
        const float* eb = &E_lds[0][s * HALF];
        const float4 e0 = ((const float4*)eb)[0], e1 = ((const float4*)eb)[1],
                     e2 = ((const float4*)eb)[2], e3 = ((const float4*)eb)[3],
                     e4 = ((const float4*)eb)[4], e5 = ((const float4*)eb)[5],
                     e6 = ((const float4*)eb)[6], e7 = ((const float4*)eb)[7],
                     e8 = ((const float4*)eb)[8];
        float a0 = 0.f, a1 = 0.f, a2 = 0.f, a3 = 0.f;
        MAC(q0, e0) MAC(q1, e1) MAC(q2, e2) MAC(q3, e3) MAC(q4, e4)
        MAC(q5, e5) MAC(q6, e6) MAC(q7, e7) MAC(q8, e8)
        const float p = (a0 + a1) + (a2 + a3);
        conn = p + dpp_xor1(p);
    }

    float* op = out + (size_t)j * (size_t)num_steps;

    for (int t = 0; t < num_steps; ++t) {
        const int cur = t & 1;

        // 1) E_t reads issue first; LDS latency hides under elementwise
        const float* eb = &E_lds[cur][s * HALF];
        const float4 e0 = ((const float4*)eb)[0], e1 = ((const float4*)eb)[1],
                     e2 = ((const float4*)eb)[2], e3 = ((const float4*)eb)[3],
                     e4 = ((const float4*)eb)[4], e5 = ((const float4*)eb)[5],
                     e6 = ((const float4*)eb)[6], e7 = ((const float4*)eb)[7],
                     e8 = ((const float4*)eb)[8];

        // 2) elementwise update with conn_t -- FAST path:
        //    1 fmaf + v_exp_f32 + v_rcp_f32 per sigmoid, mul by 1/tau
        const float xE = P1 * E - P2 * I + P5 * conn + Pp;
        const float Se = FAST_RCP(1.0f + FAST_EXP2(fmaf(kE2, xE, bE2))) - s0E;
        const float xI = P3 * E - P4 * I;                          // Q = 0
        const float Si = FAST_RCP(1.0f + FAST_EXP2(fmaf(kI2, xI, bI2))) - s0I;
        // En = E + (-E + (kE-E)*Se)/tau_e  (rE=1, DT=1)
        const float En = fmaf(fmaf(kE - E, Se, -E), inv_te, E);
        const float In = fmaf(fmaf(kI - I, Si, -I), inv_ti, I);

        // 3) publish (both lanes same-addr same-value LDS write: free)
        E_lds[cur ^ 1][j] = En;
        if (s == 0) op[t] = En - In;     // fire-and-forget, never drained

        // 4) conn_{t+1} = C @ E_t
        float a0 = 0.f, a1 = 0.f, a2 = 0.f, a3 = 0.f;
        MAC(q0, e0) MAC(q1, e1) MAC(q2, e2) MAC(q3, e3) MAC(q4, e4)
        MAC(q5, e5) MAC(q6, e6) MAC(q7, e7) MAC(q8, e8)
        const float p = (a0 + a1) + (a2 + a3);
        conn = p + dpp_xor1(p);

        E = En; I = In;
        // LDS-only barrier: never drains the output stores (vmcnt untouched)
        asm volatile("s_waitcnt lgkmcnt(0)\ns_barrier" ::: "memory");
    }
}

extern "C" void kernel_launch(void* const* d_in, const int* in_sizes, int n_in,
                              void* d_out, int out_size, void* d_ws, size_t ws_size,
                              hipStream_t stream) {
    const float* params = (const float*)d_in[0];
    const float* Cjk    = (const float*)d_in[1];
    const float* y0     = (const float*)d_in[2];
    const int num_steps = out_size / NN;

    nmm_kernel<<<dim3(1), dim3(NT), 0, stream>>>(
        params, Cjk, y0, (float*)d_out, num_steps);
}